// Round 11
// baseline (341.757 us; speedup 1.0000x reference)
//
#include <hip/hip_runtime.h>
#include <math.h>

#define NN 50000
#define NE 800000
#define DD 128
#define NBKT 196            // coarse buckets: row >> 8
#define BCAP 5120           // per-bucket capacity (mean 4082 -> 16-sigma margin)
#define CHUNK 2048          // edges per bin_kernel block
#define NCHUNK ((NE + CHUNK - 1) / CHUNK)   // 391
#define NSLICE 4            // 32-col feature slices (3.2 MB table slice < 4 MB XCD L2)
#define RB ((NN + 63) / 64) // 782 row-blocks per slice (64 rows/block)
#define CS1_NBLK 1024       // stats pass-1 blocks
#define CS_ROWS 49          // rows per pass-1 block (1024*49 >= 50000)

typedef unsigned int uiv4 __attribute__((ext_vector_type(4)));

// ---------------- bf16 helpers (x stored as bf16 pairs packed in uint) ----------------
static __device__ __forceinline__ float blo(unsigned int p) { return __uint_as_float(p << 16); }
static __device__ __forceinline__ float bhi(unsigned int p) { return __uint_as_float(p & 0xffff0000u); }
static __device__ __forceinline__ unsigned int pack2bf(float a, float b) {
    unsigned int ua = __float_as_uint(a);
    unsigned int ub = __float_as_uint(b);
    ua = ua + 0x7FFFu + ((ua >> 16) & 1u);
    ub = ub + 0x7FFFu + ((ub >> 16) & 1u);
    return (ua >> 16) | (ub & 0xffff0000u);
}

// ---------------- pass 1: LDS counting-sort edges into 196 coarse buckets ----------------
static __global__ __launch_bounds__(256) void bin_kernel(
    const int* __restrict__ erow, const int* __restrict__ ecol, const float* __restrict__ eval_,
    int* __restrict__ bucket_cursor, uint2* __restrict__ binned) {
    __shared__ uint2 sorted[CHUNK];
    __shared__ unsigned short sbin[CHUNK];
    __shared__ int hist[NBKT];
    __shared__ int bstart[NBKT];
    __shared__ int bcur[NBKT];
    __shared__ int gbase[NBKT];
    __shared__ int tmp[256];

    int t = threadIdx.x;
    int cbase = blockIdx.x * CHUNK;
    int cn = NE - cbase; if (cn > CHUNK) cn = CHUNK;

    for (int i = t; i < NBKT; i += 256) hist[i] = 0;
    __syncthreads();

    unsigned int rc[8]; unsigned int vv[8]; int bb[8];
    int nloc = 0;
    for (int i = t; i < cn; i += 256) {
        int g = cbase + i;
        int r = erow[g];
        int c = ecol[g];
        float v = eval_[g];
        rc[nloc] = (unsigned)r | ((unsigned)c << 16);
        vv[nloc] = __float_as_uint(v);
        int b = r >> 8;
        bb[nloc] = b;
        atomicAdd(&hist[b], 1);
        ++nloc;
    }
    __syncthreads();

    int hv = (t < NBKT) ? hist[t] : 0;
    tmp[t] = hv;
    __syncthreads();
    for (int off = 1; off < 256; off <<= 1) {
        int u = (t >= off) ? tmp[t - off] : 0;
        __syncthreads();
        tmp[t] += u;
        __syncthreads();
    }
    if (t < NBKT) {
        int ex = tmp[t] - hv;
        bstart[t] = ex;
        bcur[t] = ex;
        gbase[t] = atomicAdd(&bucket_cursor[t], hv);
    }
    __syncthreads();

    for (int k = 0; k < nloc; ++k) {
        int pos = atomicAdd(&bcur[bb[k]], 1);
        sorted[pos] = make_uint2(rc[k], vv[k]);
        sbin[pos] = (unsigned short)bb[k];
    }
    __syncthreads();

    for (int i = t; i < cn; i += 256) {
        int b = sbin[i];
        binned[(size_t)b * BCAP + gbase[b] + (i - bstart[b])] = sorted[i];
    }
}

// ---------------- pass 2: per-bucket sort by row -> CSR + row_start + deg + x0 ----------
static __global__ __launch_bounds__(256) void sort_kernel(
    const uint2* __restrict__ binned, const int* __restrict__ bucket_cursor,
    uint2* __restrict__ csr, int* __restrict__ row_start, float* __restrict__ deg,
    const float* __restrict__ R, uint4* __restrict__ x0) {
    __shared__ uint2 buf[BCAP];
    __shared__ int hist[256];
    __shared__ int rcur[256];
    __shared__ float fdeg[256];
    __shared__ int pscan[256];
    int b = blockIdx.x;
    int t = threadIdx.x;
    int lo = b << 8;

    int pv = (t < NBKT) ? bucket_cursor[t] : 0;
    pscan[t] = pv;
    hist[t] = 0;
    fdeg[t] = 0.0f;
    __syncthreads();
    for (int off = 1; off < 256; off <<= 1) {
        int u = (t >= off) ? pscan[t - off] : 0;
        __syncthreads();
        pscan[t] += u;
        __syncthreads();
    }
    int gb = (b == 0) ? 0 : pscan[b - 1];
    int cnt = pscan[b] - gb;

    for (int i = t; i < cnt; i += 256) {
        uint2 e = binned[(size_t)b * BCAP + i];
        buf[i] = e;
        int rr = (int)(e.x & 0xFFFFu) - lo;
        atomicAdd(&hist[rr], 1);
        atomicAdd(&fdeg[rr], __uint_as_float(e.y));
    }
    __syncthreads();
    int hv = hist[t];
    rcur[t] = hv;
    __syncthreads();
    for (int off = 1; off < 256; off <<= 1) {
        int u = (t >= off) ? rcur[t - off] : 0;
        __syncthreads();
        rcur[t] += u;
        __syncthreads();
    }
    int excl = rcur[t] - hv;
    int r = lo + t;
    if (r < NN) {
        row_start[r] = gb + excl;
        float d = fdeg[t];
        deg[r] = (d == 0.0f) ? 1.0f : d;
    }
    if (b == NBKT - 1 && t == 255) row_start[NN] = gb + cnt;
    rcur[t] = excl;
    __syncthreads();
    for (int i = t; i < cnt; i += 256) {
        uint2 e = buf[i];
        int rr = (int)(e.x & 0xFFFFu) - lo;
        int pos = atomicAdd(&rcur[rr], 1);
        csr[(size_t)gb + pos] = make_uint2(e.x >> 16, e.y);
    }

    int nrows = NN - lo; if (nrows > 256) nrows = 256;
    const float4* __restrict__ R4 = (const float4*)R;
    for (int idx = t; idx < nrows * 16; idx += 256) {
        int rr = idx >> 4;
        int sub = idx & 15;
        float d = fdeg[rr];
        d = (d == 0.0f) ? 1.0f : d;
        float sc = rsqrtf(d);
        size_t g = (size_t)(lo + rr) * 16 + sub;
        float4 f0 = R4[g * 2];
        float4 f1 = R4[g * 2 + 1];
        x0[g] = make_uint4(pack2bf(f0.x * sc, f0.y * sc), pack2bf(f0.z * sc, f0.w * sc),
                           pack2bf(f1.x * sc, f1.y * sc), pack2bf(f1.z * sc, f1.w * sc));
    }
}

// ---------------- sliced SpMM hop: 32-col slice kept L2-resident ----------------
// grid = NSLICE * RB blocks (slice-major). 4-lane group per row; lane owns 8 cols
// (one uint4). Writes unnormalized inv-deg-scaled x_out slice (nontemporal) +
// per-(slice,row) norm partial. No cross-slice dependency inside the kernel.
static __global__ __launch_bounds__(256) void spmm_slice_kernel(
    const int* __restrict__ row_start, const uint2* __restrict__ csr,
    const uint4* __restrict__ xin, const float* __restrict__ deg,
    uint4* __restrict__ xout, float* __restrict__ ssp) {
    int slice = blockIdx.x / RB;
    int blk = blockIdx.x - slice * RB;
    int t = threadIdx.x;
    int l4 = t & 3;
    int row = blk * 64 + (t >> 2);
    if (row >= NN) return;
    int wb = (t & 63) & ~3;  // group base lane within the wave
    int s = row_start[row];
    int e = row_start[row + 1];
    int sl4 = slice * 4 + l4;

    float a0 = 0.f, a1 = 0.f, a2 = 0.f, a3 = 0.f, a4 = 0.f, a5 = 0.f, a6 = 0.f, a7 = 0.f;
    int base = s;
    for (; base + 4 <= e; base += 4) {
        uint2 t2 = csr[base + l4];
        int cl = (int)t2.x;
        float vl = __uint_as_float(t2.y);
        int c0 = __shfl(cl, wb);
        int c1 = __shfl(cl, wb + 1);
        int c2 = __shfl(cl, wb + 2);
        int c3 = __shfl(cl, wb + 3);
        float v0 = __shfl(vl, wb);
        float v1 = __shfl(vl, wb + 1);
        float v2 = __shfl(vl, wb + 2);
        float v3 = __shfl(vl, wb + 3);
        uint4 p0 = xin[(size_t)c0 * 16 + sl4];
        uint4 p1 = xin[(size_t)c1 * 16 + sl4];
        uint4 p2 = xin[(size_t)c2 * 16 + sl4];
        uint4 p3 = xin[(size_t)c3 * 16 + sl4];
        a0 += v0 * blo(p0.x); a1 += v0 * bhi(p0.x); a2 += v0 * blo(p0.y); a3 += v0 * bhi(p0.y);
        a4 += v0 * blo(p0.z); a5 += v0 * bhi(p0.z); a6 += v0 * blo(p0.w); a7 += v0 * bhi(p0.w);
        a0 += v1 * blo(p1.x); a1 += v1 * bhi(p1.x); a2 += v1 * blo(p1.y); a3 += v1 * bhi(p1.y);
        a4 += v1 * blo(p1.z); a5 += v1 * bhi(p1.z); a6 += v1 * blo(p1.w); a7 += v1 * bhi(p1.w);
        a0 += v2 * blo(p2.x); a1 += v2 * bhi(p2.x); a2 += v2 * blo(p2.y); a3 += v2 * bhi(p2.y);
        a4 += v2 * blo(p2.z); a5 += v2 * bhi(p2.z); a6 += v2 * blo(p2.w); a7 += v2 * bhi(p2.w);
        a0 += v3 * blo(p3.x); a1 += v3 * bhi(p3.x); a2 += v3 * blo(p3.y); a3 += v3 * bhi(p3.y);
        a4 += v3 * blo(p3.z); a5 += v3 * bhi(p3.z); a6 += v3 * blo(p3.w); a7 += v3 * bhi(p3.w);
    }
    if (base < e) {  // tail 1..3 neighbors
        int j = base + l4;
        int cl = 0; float vl = 0.0f;
        if (j < e) { uint2 t2 = csr[j]; cl = (int)t2.x; vl = __uint_as_float(t2.y); }
        int cnt = e - base;
        for (int k = 0; k < cnt; ++k) {
            int c = __shfl(cl, wb + k);
            float v = __shfl(vl, wb + k);
            uint4 p = xin[(size_t)c * 16 + sl4];
            a0 += v * blo(p.x); a1 += v * bhi(p.x); a2 += v * blo(p.y); a3 += v * bhi(p.y);
            a4 += v * blo(p.z); a5 += v * bhi(p.z); a6 += v * blo(p.w); a7 += v * bhi(p.w);
        }
    }

    float id = 1.0f / deg[row];
    a0 *= id; a1 *= id; a2 *= id; a3 *= id; a4 *= id; a5 *= id; a6 *= id; a7 *= id;

    float ss = a0 * a0 + a1 * a1 + a2 * a2 + a3 * a3 + a4 * a4 + a5 * a5 + a6 * a6 + a7 * a7;
    ss += __shfl_xor(ss, 1);
    ss += __shfl_xor(ss, 2);

    uiv4 o = { pack2bf(a0, a1), pack2bf(a2, a3), pack2bf(a4, a5), pack2bf(a6, a7) };
    __builtin_nontemporal_store(o, (uiv4*)&xout[(size_t)row * 16 + sl4]);
    if (l4 == 0) ssp[(size_t)slice * NN + row] = ss;
}

// ---------------- finalize per-row scales from slice norm partials ----------------
static __global__ __launch_bounds__(256) void s_kernel(
    const float* __restrict__ ssp,  // [4 hops][NSLICE][NN]
    float* __restrict__ s1, float* __restrict__ s2,
    float* __restrict__ s3, float* __restrict__ s4) {
    int r = blockIdx.x * blockDim.x + threadIdx.x;
    if (r >= NN) return;
    const float w[4] = {1.0f, 1.0f, 7.81f, 45.28f};
    float* sout[4] = {s1, s2, s3, s4};
#pragma unroll
    for (int h = 0; h < 4; ++h) {
        const float* p = ssp + (size_t)h * NSLICE * NN;
        float ss = p[r] + p[NN + r] + p[2 * NN + r] + p[3 * NN + r];
        float nrm = fmaxf(sqrtf(ss), 1e-12f);
        sout[h][r] = w[h] / nrm;
    }
}

// ---------------- column partial stats from the 4 bf16 hops ----------------
static __global__ __launch_bounds__(256) void stats_kernel(
    const uint4* __restrict__ x1, const uint4* __restrict__ x2,
    const uint4* __restrict__ x3, const uint4* __restrict__ x4,
    const float* __restrict__ s1, const float* __restrict__ s2,
    const float* __restrict__ s3, const float* __restrict__ s4,
    double* __restrict__ psum, double* __restrict__ psumsq) {
    __shared__ double shs[256 * 8];
    __shared__ double shq[256 * 8];
    int t = threadIdx.x;
    int sub = t & 15;
    int ro = t >> 4;
    int rbeg = blockIdx.x * CS_ROWS;
    int rend = rbeg + CS_ROWS; if (rend > NN) rend = NN;

    double ls[8], lq[8];
#pragma unroll
    for (int j = 0; j < 8; ++j) { ls[j] = 0.0; lq[j] = 0.0; }

    for (int r = rbeg + ro; r < rend; r += 16) {
        float w1 = s1[r], w2 = s2[r], w3 = s3[r], w4 = s4[r];
        size_t xi = (size_t)r * 16 + sub;
        uint4 q1 = x1[xi], q2 = x2[xi], q3 = x3[xi], q4 = x4[xi];
        float v[8];
        v[0] = w1 * blo(q1.x) + w2 * blo(q2.x) + w3 * blo(q3.x) + w4 * blo(q4.x);
        v[1] = w1 * bhi(q1.x) + w2 * bhi(q2.x) + w3 * bhi(q3.x) + w4 * bhi(q4.x);
        v[2] = w1 * blo(q1.y) + w2 * blo(q2.y) + w3 * blo(q3.y) + w4 * blo(q4.y);
        v[3] = w1 * bhi(q1.y) + w2 * bhi(q2.y) + w3 * bhi(q3.y) + w4 * bhi(q4.y);
        v[4] = w1 * blo(q1.z) + w2 * blo(q2.z) + w3 * blo(q3.z) + w4 * blo(q4.z);
        v[5] = w1 * bhi(q1.z) + w2 * bhi(q2.z) + w3 * bhi(q3.z) + w4 * bhi(q4.z);
        v[6] = w1 * blo(q1.w) + w2 * blo(q2.w) + w3 * blo(q3.w) + w4 * blo(q4.w);
        v[7] = w1 * bhi(q1.w) + w2 * bhi(q2.w) + w3 * bhi(q3.w) + w4 * bhi(q4.w);
#pragma unroll
        for (int j = 0; j < 8; ++j) { ls[j] += (double)v[j]; lq[j] += (double)v[j] * (double)v[j]; }
    }
#pragma unroll
    for (int j = 0; j < 8; ++j) { shs[t * 8 + j] = ls[j]; shq[t * 8 + j] = lq[j]; }
    __syncthreads();
    if (t < DD) {
        int cs = t >> 3, cj = t & 7;
        double s = 0.0, q = 0.0;
        for (int g = 0; g < 16; ++g) {
            int src = (g * 16 + cs) * 8 + cj;
            s += shs[src];
            q += shq[src];
        }
        psum[(size_t)blockIdx.x * DD + t] = s;
        psumsq[(size_t)blockIdx.x * DD + t] = q;
    }
}

// ---------------- fold partials per column, compute mean/invstd ----------------
static __global__ __launch_bounds__(256) void fold_kernel(
    const double* __restrict__ psum, const double* __restrict__ psumsq,
    float* __restrict__ mean, float* __restrict__ invstd) {
    __shared__ double ss[256], qq[256];
    int c = blockIdx.x;
    int t = threadIdx.x;
    double s = 0.0, q = 0.0;
    for (int b = t; b < CS1_NBLK; b += 256) {
        s += psum[(size_t)b * DD + c];
        q += psumsq[(size_t)b * DD + c];
    }
    ss[t] = s; qq[t] = q;
    __syncthreads();
    for (int off = 128; off > 0; off >>= 1) {
        if (t < off) { ss[t] += ss[t + off]; qq[t] += qq[t + off]; }
        __syncthreads();
    }
    if (t == 0) {
        double m = ss[0] / (double)NN;
        double var = (qq[0] - (double)NN * m * m) / (double)(NN - 1);
        if (var < 0.0) var = 0.0;
        double sd = sqrt(var);
        if (sd == 0.0) sd = 1.0;
        mean[c] = (float)m;
        invstd[c] = (float)(1.0 / sd);
    }
}

// ---------------- final: reconstruct acc from hops, standardize, write out ----------------
static __global__ __launch_bounds__(256) void final_kernel(
    const uint4* __restrict__ x1, const uint4* __restrict__ x2,
    const uint4* __restrict__ x3, const uint4* __restrict__ x4,
    const float* __restrict__ s1, const float* __restrict__ s2,
    const float* __restrict__ s3, const float* __restrict__ s4,
    const float* __restrict__ mean, const float* __restrict__ invstd,
    float* __restrict__ out) {
    int i = blockIdx.x * blockDim.x + threadIdx.x;  // over NN*16
    int r = i >> 4;
    int sub = i & 15;
    float w1 = s1[r], w2 = s2[r], w3 = s3[r], w4 = s4[r];
    uint4 q1 = x1[i], q2 = x2[i], q3 = x3[i], q4 = x4[i];
    float v[8];
    v[0] = w1 * blo(q1.x) + w2 * blo(q2.x) + w3 * blo(q3.x) + w4 * blo(q4.x);
    v[1] = w1 * bhi(q1.x) + w2 * bhi(q2.x) + w3 * bhi(q3.x) + w4 * bhi(q4.x);
    v[2] = w1 * blo(q1.y) + w2 * blo(q2.y) + w3 * blo(q3.y) + w4 * blo(q4.y);
    v[3] = w1 * bhi(q1.y) + w2 * bhi(q2.y) + w3 * bhi(q3.y) + w4 * bhi(q4.y);
    v[4] = w1 * blo(q1.z) + w2 * blo(q2.z) + w3 * blo(q3.z) + w4 * blo(q4.z);
    v[5] = w1 * bhi(q1.z) + w2 * bhi(q2.z) + w3 * bhi(q3.z) + w4 * bhi(q4.z);
    v[6] = w1 * blo(q1.w) + w2 * blo(q2.w) + w3 * blo(q3.w) + w4 * blo(q4.w);
    v[7] = w1 * bhi(q1.w) + w2 * bhi(q2.w) + w3 * bhi(q3.w) + w4 * bhi(q4.w);
    const float4* m4 = (const float4*)mean;
    const float4* is4 = (const float4*)invstd;
    float4 m0 = m4[sub * 2], m1 = m4[sub * 2 + 1];
    float4 i0 = is4[sub * 2], i1 = is4[sub * 2 + 1];
    float4* out4 = (float4*)out;
    out4[(size_t)i * 2]     = make_float4((v[0] - m0.x) * i0.x, (v[1] - m0.y) * i0.y,
                                          (v[2] - m0.z) * i0.z, (v[3] - m0.w) * i0.w);
    out4[(size_t)i * 2 + 1] = make_float4((v[4] - m1.x) * i1.x, (v[5] - m1.y) * i1.y,
                                          (v[6] - m1.z) * i1.z, (v[7] - m1.w) * i1.w);
}

extern "C" void kernel_launch(void* const* d_in, const int* in_sizes, int n_in,
                              void* d_out, int out_size, void* d_ws, size_t ws_size,
                              hipStream_t stream) {
    const int* erow = (const int*)d_in[0];
    const int* ecol = (const int*)d_in[1];
    const float* eval_ = (const float*)d_in[2];
    const float* R = (const float*)d_in[3];
    float* out = (float*)d_out;

    char* ws = (char*)d_ws;
    size_t off = 0;
    auto alloc = [&](size_t bytes) -> char* {
        char* p = ws + off;
        off += (bytes + 255) & ~(size_t)255;
        return p;
    };
    float* deg          = (float*)alloc(NN * sizeof(float));
    int* bucket_cursor  = (int*)alloc(NBKT * sizeof(int));
    int* row_start      = (int*)alloc((NN + 1) * sizeof(int));
    uint2* binned       = (uint2*)alloc((size_t)NBKT * BCAP * sizeof(uint2));
    uint2* csr          = (uint2*)alloc((size_t)NE * sizeof(uint2));
    uint4* x0           = (uint4*)alloc((size_t)NN * 16 * sizeof(uint4));  // bf16 packed
    uint4* x1           = (uint4*)alloc((size_t)NN * 16 * sizeof(uint4));
    uint4* x2           = (uint4*)alloc((size_t)NN * 16 * sizeof(uint4));
    uint4* x3           = (uint4*)alloc((size_t)NN * 16 * sizeof(uint4));
    uint4* x4           = (uint4*)alloc((size_t)NN * 16 * sizeof(uint4));
    float* ssp          = (float*)alloc((size_t)4 * NSLICE * NN * sizeof(float));
    float* s1           = (float*)alloc(NN * sizeof(float));
    float* s2           = (float*)alloc(NN * sizeof(float));
    float* s3           = (float*)alloc(NN * sizeof(float));
    float* s4           = (float*)alloc(NN * sizeof(float));
    double* psum        = (double*)alloc((size_t)CS1_NBLK * DD * sizeof(double));
    double* psumsq      = (double*)alloc((size_t)CS1_NBLK * DD * sizeof(double));
    float* meanbuf      = (float*)alloc(DD * sizeof(float));
    float* invstdb      = (float*)alloc(DD * sizeof(float));

    hipMemsetAsync(bucket_cursor, 0, NBKT * sizeof(int), stream);

    bin_kernel<<<NCHUNK, 256, 0, stream>>>(erow, ecol, eval_, bucket_cursor, binned);
    sort_kernel<<<NBKT, 256, 0, stream>>>(binned, bucket_cursor, csr, row_start, deg, R, x0);

    const int hop_grid = NSLICE * RB;
    spmm_slice_kernel<<<hop_grid, 256, 0, stream>>>(row_start, csr, x0, deg, x1,
                                                    ssp + 0 * NSLICE * NN);
    spmm_slice_kernel<<<hop_grid, 256, 0, stream>>>(row_start, csr, x1, deg, x2,
                                                    ssp + 1 * NSLICE * NN);
    spmm_slice_kernel<<<hop_grid, 256, 0, stream>>>(row_start, csr, x2, deg, x3,
                                                    ssp + 2 * NSLICE * NN);
    spmm_slice_kernel<<<hop_grid, 256, 0, stream>>>(row_start, csr, x3, deg, x4,
                                                    ssp + 3 * NSLICE * NN);

    s_kernel<<<(NN + 255) / 256, 256, 0, stream>>>(ssp, s1, s2, s3, s4);
    stats_kernel<<<CS1_NBLK, 256, 0, stream>>>(x1, x2, x3, x4, s1, s2, s3, s4, psum, psumsq);
    fold_kernel<<<DD, 256, 0, stream>>>(psum, psumsq, meanbuf, invstdb);
    final_kernel<<<NN * 16 / 256, 256, 0, stream>>>(x1, x2, x3, x4, s1, s2, s3, s4,
                                                    meanbuf, invstdb, out);
}

// Round 13
// 261.830 us; speedup vs baseline: 1.3053x; 1.3053x over previous
//
#include <hip/hip_runtime.h>
#include <math.h>

#define NN 50000
#define NE 800000
#define DD 128
#define NBKT 196            // coarse buckets: row >> 8
#define BCAP 5120           // per-bucket capacity (mean 4082 -> 16-sigma margin)
#define CHUNK 2048          // edges per bin_kernel block
#define NCHUNK ((NE + CHUNK - 1) / CHUNK)   // 391
#define SPMM_NBLK (NN / 16) // 3125

typedef unsigned int uiv2 __attribute__((ext_vector_type(2)));
typedef unsigned int uiv4 __attribute__((ext_vector_type(4)));

// ---------------- bf16 helpers (x stored as bf16 pairs packed in uint) ----------------
static __device__ __forceinline__ float blo(unsigned int p) { return __uint_as_float(p << 16); }
static __device__ __forceinline__ float bhi(unsigned int p) { return __uint_as_float(p & 0xffff0000u); }
static __device__ __forceinline__ unsigned int pack2bf(float a, float b) {
    unsigned int ua = __float_as_uint(a);
    unsigned int ub = __float_as_uint(b);
    ua = ua + 0x7FFFu + ((ua >> 16) & 1u);
    ub = ub + 0x7FFFu + ((ub >> 16) & 1u);
    return (ua >> 16) | (ub & 0xffff0000u);
}

// ---------------- pass 1: LDS counting-sort edges into 196 coarse buckets ----------------
// payload: uint2{ row | col<<16, val_bits }  (row, col < 65536)
static __global__ __launch_bounds__(256) void bin_kernel(
    const int* __restrict__ erow, const int* __restrict__ ecol, const float* __restrict__ eval_,
    int* __restrict__ bucket_cursor, uint2* __restrict__ binned) {
    __shared__ uint2 sorted[CHUNK];
    __shared__ unsigned short sbin[CHUNK];
    __shared__ int hist[NBKT];
    __shared__ int bstart[NBKT];
    __shared__ int bcur[NBKT];
    __shared__ int gbase[NBKT];
    __shared__ int tmp[256];

    int t = threadIdx.x;
    int cbase = blockIdx.x * CHUNK;
    int cn = NE - cbase; if (cn > CHUNK) cn = CHUNK;

    for (int i = t; i < NBKT; i += 256) hist[i] = 0;
    __syncthreads();

    unsigned int rc[8]; unsigned int vv[8]; int bb[8];
    int nloc = 0;
    for (int i = t; i < cn; i += 256) {
        int g = cbase + i;
        int r = erow[g];
        int c = ecol[g];
        float v = eval_[g];
        rc[nloc] = (unsigned)r | ((unsigned)c << 16);
        vv[nloc] = __float_as_uint(v);
        int b = r >> 8;
        bb[nloc] = b;
        atomicAdd(&hist[b], 1);
        ++nloc;
    }
    __syncthreads();

    int hv = (t < NBKT) ? hist[t] : 0;
    tmp[t] = hv;
    __syncthreads();
    for (int off = 1; off < 256; off <<= 1) {
        int u = (t >= off) ? tmp[t - off] : 0;
        __syncthreads();
        tmp[t] += u;
        __syncthreads();
    }
    if (t < NBKT) {
        int ex = tmp[t] - hv;
        bstart[t] = ex;
        bcur[t] = ex;
        gbase[t] = atomicAdd(&bucket_cursor[t], hv);
    }
    __syncthreads();

    for (int k = 0; k < nloc; ++k) {
        int pos = atomicAdd(&bcur[bb[k]], 1);
        sorted[pos] = make_uint2(rc[k], vv[k]);
        sbin[pos] = (unsigned short)bb[k];
    }
    __syncthreads();

    for (int i = t; i < cn; i += 256) {
        int b = sbin[i];
        binned[(size_t)b * BCAP + gbase[b] + (i - bstart[b])] = sorted[i];
    }
}

// ---------------- pass 2: per-bucket sort by row -> CSR + row_start + deg + x0 ----------
static __global__ __launch_bounds__(256) void sort_kernel(
    const uint2* __restrict__ binned, const int* __restrict__ bucket_cursor,
    uint2* __restrict__ csr, int* __restrict__ row_start, float* __restrict__ deg,
    const float* __restrict__ R, uint4* __restrict__ x0) {
    __shared__ uint2 buf[BCAP];
    __shared__ int hist[256];
    __shared__ int rcur[256];
    __shared__ float fdeg[256];
    __shared__ int pscan[256];
    int b = blockIdx.x;
    int t = threadIdx.x;
    int lo = b << 8;

    int pv = (t < NBKT) ? bucket_cursor[t] : 0;
    pscan[t] = pv;
    hist[t] = 0;
    fdeg[t] = 0.0f;
    __syncthreads();
    for (int off = 1; off < 256; off <<= 1) {
        int u = (t >= off) ? pscan[t - off] : 0;
        __syncthreads();
        pscan[t] += u;
        __syncthreads();
    }
    int gb = (b == 0) ? 0 : pscan[b - 1];
    int cnt = pscan[b] - gb;

    for (int i = t; i < cnt; i += 256) {
        uint2 e = binned[(size_t)b * BCAP + i];
        buf[i] = e;
        int rr = (int)(e.x & 0xFFFFu) - lo;
        atomicAdd(&hist[rr], 1);
        atomicAdd(&fdeg[rr], __uint_as_float(e.y));
    }
    __syncthreads();
    int hv = hist[t];
    rcur[t] = hv;
    __syncthreads();
    for (int off = 1; off < 256; off <<= 1) {
        int u = (t >= off) ? rcur[t - off] : 0;
        __syncthreads();
        rcur[t] += u;
        __syncthreads();
    }
    int excl = rcur[t] - hv;
    int r = lo + t;
    if (r < NN) {
        row_start[r] = gb + excl;
        float d = fdeg[t];
        deg[r] = (d == 0.0f) ? 1.0f : d;
    }
    if (b == NBKT - 1 && t == 255) row_start[NN] = gb + cnt;
    rcur[t] = excl;
    __syncthreads();
    for (int i = t; i < cnt; i += 256) {
        uint2 e = buf[i];
        int rr = (int)(e.x & 0xFFFFu) - lo;
        int pos = atomicAdd(&rcur[rr], 1);
        csr[(size_t)gb + pos] = make_uint2(e.x >> 16, e.y);
    }

    int nrows = NN - lo; if (nrows > 256) nrows = 256;
    const float4* __restrict__ R4 = (const float4*)R;
    for (int idx = t; idx < nrows * 16; idx += 256) {
        int rr = idx >> 4;
        int sub = idx & 15;
        float d = fdeg[rr];
        d = (d == 0.0f) ? 1.0f : d;
        float sc = rsqrtf(d);
        size_t g = (size_t)(lo + rr) * 16 + sub;
        float4 f0 = R4[g * 2];
        float4 f1 = R4[g * 2 + 1];
        x0[g] = make_uint4(pack2bf(f0.x * sc, f0.y * sc), pack2bf(f0.z * sc, f0.w * sc),
                           pack2bf(f1.x * sc, f1.y * sc), pack2bf(f1.z * sc, f1.w * sc));
    }
}

// ---------------- fused SpMM + inv_deg + row-norm scalar (hops 1-3) ----------------
// 256 threads = 4 waves; each wave handles 4 rows, one per 16-lane quarter.
// NT loads for the csr stream (zero reuse) keep L2 for the gather table.
// 8 gathers in flight per lane.
static __global__ __launch_bounds__(256) void spmm_fused_kernel(
    const int* __restrict__ row_start, const uint2* __restrict__ csr,
    const uint4* __restrict__ xin, const float* __restrict__ deg,
    uint4* __restrict__ x_next4, float* __restrict__ s_out, float weight) {
    int wave = threadIdx.x >> 6;
    int lane = threadIdx.x & 63;
    int quarter = lane >> 4;
    int sub = lane & 15;
    int row = blockIdx.x * 16 + wave * 4 + quarter;
    int s = row_start[row];
    int e = row_start[row + 1];

    float a0 = 0.f, a1 = 0.f, a2 = 0.f, a3 = 0.f, a4 = 0.f, a5 = 0.f, a6 = 0.f, a7 = 0.f;
    for (int base = s; base < e; base += 16) {
        int j = base + sub;
        int cl = 0;
        float vl = 0.0f;
        if (j < e) {
            uiv2 t2 = __builtin_nontemporal_load((const uiv2*)&csr[j]);
            cl = (int)t2.x; vl = __uint_as_float(t2.y);
        }
        int cnt = e - base; if (cnt > 16) cnt = 16;
        for (int k = 0; k < cnt; k += 8) {  // 8 gathers in flight; v=0 for entries past cnt
            int l0 = quarter * 16 + k;
            int c0 = __shfl(cl, l0);
            int c1 = __shfl(cl, l0 + 1);
            int c2 = __shfl(cl, l0 + 2);
            int c3 = __shfl(cl, l0 + 3);
            int c4 = __shfl(cl, l0 + 4);
            int c5 = __shfl(cl, l0 + 5);
            int c6 = __shfl(cl, l0 + 6);
            int c7 = __shfl(cl, l0 + 7);
            float v0 = __shfl(vl, l0);
            float v1 = __shfl(vl, l0 + 1);
            float v2 = __shfl(vl, l0 + 2);
            float v3 = __shfl(vl, l0 + 3);
            float v4 = __shfl(vl, l0 + 4);
            float v5 = __shfl(vl, l0 + 5);
            float v6 = __shfl(vl, l0 + 6);
            float v7 = __shfl(vl, l0 + 7);
            uint4 p0 = xin[(size_t)c0 * 16 + sub];
            uint4 p1 = xin[(size_t)c1 * 16 + sub];
            uint4 p2 = xin[(size_t)c2 * 16 + sub];
            uint4 p3 = xin[(size_t)c3 * 16 + sub];
            uint4 p4 = xin[(size_t)c4 * 16 + sub];
            uint4 p5 = xin[(size_t)c5 * 16 + sub];
            uint4 p6 = xin[(size_t)c6 * 16 + sub];
            uint4 p7 = xin[(size_t)c7 * 16 + sub];
            a0 += v0 * blo(p0.x); a1 += v0 * bhi(p0.x); a2 += v0 * blo(p0.y); a3 += v0 * bhi(p0.y);
            a4 += v0 * blo(p0.z); a5 += v0 * bhi(p0.z); a6 += v0 * blo(p0.w); a7 += v0 * bhi(p0.w);
            a0 += v1 * blo(p1.x); a1 += v1 * bhi(p1.x); a2 += v1 * blo(p1.y); a3 += v1 * bhi(p1.y);
            a4 += v1 * blo(p1.z); a5 += v1 * bhi(p1.z); a6 += v1 * blo(p1.w); a7 += v1 * bhi(p1.w);
            a0 += v2 * blo(p2.x); a1 += v2 * bhi(p2.x); a2 += v2 * blo(p2.y); a3 += v2 * bhi(p2.y);
            a4 += v2 * blo(p2.z); a5 += v2 * bhi(p2.z); a6 += v2 * blo(p2.w); a7 += v2 * bhi(p2.w);
            a0 += v3 * blo(p3.x); a1 += v3 * bhi(p3.x); a2 += v3 * blo(p3.y); a3 += v3 * bhi(p3.y);
            a4 += v3 * blo(p3.z); a5 += v3 * bhi(p3.z); a6 += v3 * blo(p3.w); a7 += v3 * bhi(p3.w);
            a0 += v4 * blo(p4.x); a1 += v4 * bhi(p4.x); a2 += v4 * blo(p4.y); a3 += v4 * bhi(p4.y);
            a4 += v4 * blo(p4.z); a5 += v4 * bhi(p4.z); a6 += v4 * blo(p4.w); a7 += v4 * bhi(p4.w);
            a0 += v5 * blo(p5.x); a1 += v5 * bhi(p5.x); a2 += v5 * blo(p5.y); a3 += v5 * bhi(p5.y);
            a4 += v5 * blo(p5.z); a5 += v5 * bhi(p5.z); a6 += v5 * blo(p5.w); a7 += v5 * bhi(p5.w);
            a0 += v6 * blo(p6.x); a1 += v6 * bhi(p6.x); a2 += v6 * blo(p6.y); a3 += v6 * bhi(p6.y);
            a4 += v6 * blo(p6.z); a5 += v6 * bhi(p6.z); a6 += v6 * blo(p6.w); a7 += v6 * bhi(p6.w);
            a0 += v7 * blo(p7.x); a1 += v7 * bhi(p7.x); a2 += v7 * blo(p7.y); a3 += v7 * bhi(p7.y);
            a4 += v7 * blo(p7.z); a5 += v7 * bhi(p7.z); a6 += v7 * blo(p7.w); a7 += v7 * bhi(p7.w);
        }
    }

    float id = 1.0f / deg[row];
    a0 *= id; a1 *= id; a2 *= id; a3 *= id; a4 *= id; a5 *= id; a6 *= id; a7 *= id;

    float ss = a0 * a0 + a1 * a1 + a2 * a2 + a3 * a3 + a4 * a4 + a5 * a5 + a6 * a6 + a7 * a7;
#pragma unroll
    for (int m = 1; m <= 8; m <<= 1) ss += __shfl_xor(ss, m);
    float nrm = fmaxf(sqrtf(ss), 1e-12f);

    x_next4[(size_t)row * 16 + sub] = make_uint4(pack2bf(a0, a1), pack2bf(a2, a3),
                                                 pack2bf(a4, a5), pack2bf(a6, a7));
    if (sub == 0) s_out[row] = weight / nrm;
}

// ---------------- hop 4: SpMM + combine acc(out) + per-block column stats ----------------
static __global__ __launch_bounds__(256) void spmm_last_kernel(
    const int* __restrict__ row_start, const uint2* __restrict__ csr,
    const uint4* __restrict__ xin, const float* __restrict__ deg,
    const uint4* __restrict__ x1, const uint4* __restrict__ x2, const uint4* __restrict__ x3,
    const float* __restrict__ s1, const float* __restrict__ s2, const float* __restrict__ s3,
    float* __restrict__ out, float* __restrict__ psum, float* __restrict__ psumsq, float weight) {
    __shared__ float shs[256 * 8];
    __shared__ float shq[256 * 8];
    int wave = threadIdx.x >> 6;
    int lane = threadIdx.x & 63;
    int quarter = lane >> 4;
    int sub = lane & 15;
    int row = blockIdx.x * 16 + wave * 4 + quarter;
    int s = row_start[row];
    int e = row_start[row + 1];

    float a0 = 0.f, a1 = 0.f, a2 = 0.f, a3 = 0.f, a4 = 0.f, a5 = 0.f, a6 = 0.f, a7 = 0.f;
    for (int base = s; base < e; base += 16) {
        int j = base + sub;
        int cl = 0;
        float vl = 0.0f;
        if (j < e) {
            uiv2 t2 = __builtin_nontemporal_load((const uiv2*)&csr[j]);
            cl = (int)t2.x; vl = __uint_as_float(t2.y);
        }
        int cnt = e - base; if (cnt > 16) cnt = 16;
        for (int k = 0; k < cnt; k += 8) {
            int l0 = quarter * 16 + k;
            int c0 = __shfl(cl, l0);
            int c1 = __shfl(cl, l0 + 1);
            int c2 = __shfl(cl, l0 + 2);
            int c3 = __shfl(cl, l0 + 3);
            int c4 = __shfl(cl, l0 + 4);
            int c5 = __shfl(cl, l0 + 5);
            int c6 = __shfl(cl, l0 + 6);
            int c7 = __shfl(cl, l0 + 7);
            float v0 = __shfl(vl, l0);
            float v1 = __shfl(vl, l0 + 1);
            float v2 = __shfl(vl, l0 + 2);
            float v3 = __shfl(vl, l0 + 3);
            float v4 = __shfl(vl, l0 + 4);
            float v5 = __shfl(vl, l0 + 5);
            float v6 = __shfl(vl, l0 + 6);
            float v7 = __shfl(vl, l0 + 7);
            uint4 p0 = xin[(size_t)c0 * 16 + sub];
            uint4 p1 = xin[(size_t)c1 * 16 + sub];
            uint4 p2 = xin[(size_t)c2 * 16 + sub];
            uint4 p3 = xin[(size_t)c3 * 16 + sub];
            uint4 p4 = xin[(size_t)c4 * 16 + sub];
            uint4 p5 = xin[(size_t)c5 * 16 + sub];
            uint4 p6 = xin[(size_t)c6 * 16 + sub];
            uint4 p7 = xin[(size_t)c7 * 16 + sub];
            a0 += v0 * blo(p0.x); a1 += v0 * bhi(p0.x); a2 += v0 * blo(p0.y); a3 += v0 * bhi(p0.y);
            a4 += v0 * blo(p0.z); a5 += v0 * bhi(p0.z); a6 += v0 * blo(p0.w); a7 += v0 * bhi(p0.w);
            a0 += v1 * blo(p1.x); a1 += v1 * bhi(p1.x); a2 += v1 * blo(p1.y); a3 += v1 * bhi(p1.y);
            a4 += v1 * blo(p1.z); a5 += v1 * bhi(p1.z); a6 += v1 * blo(p1.w); a7 += v1 * bhi(p1.w);
            a0 += v2 * blo(p2.x); a1 += v2 * bhi(p2.x); a2 += v2 * blo(p2.y); a3 += v2 * bhi(p2.y);
            a4 += v2 * blo(p2.z); a5 += v2 * bhi(p2.z); a6 += v2 * blo(p2.w); a7 += v2 * bhi(p2.w);
            a0 += v3 * blo(p3.x); a1 += v3 * bhi(p3.x); a2 += v3 * blo(p3.y); a3 += v3 * bhi(p3.y);
            a4 += v3 * blo(p3.z); a5 += v3 * bhi(p3.z); a6 += v3 * blo(p3.w); a7 += v3 * bhi(p3.w);
            a0 += v4 * blo(p4.x); a1 += v4 * bhi(p4.x); a2 += v4 * blo(p4.y); a3 += v4 * bhi(p4.y);
            a4 += v4 * blo(p4.z); a5 += v4 * bhi(p4.z); a6 += v4 * blo(p4.w); a7 += v4 * bhi(p4.w);
            a0 += v5 * blo(p5.x); a1 += v5 * bhi(p5.x); a2 += v5 * blo(p5.y); a3 += v5 * bhi(p5.y);
            a4 += v5 * blo(p5.z); a5 += v5 * bhi(p5.z); a6 += v5 * blo(p5.w); a7 += v5 * bhi(p5.w);
            a0 += v6 * blo(p6.x); a1 += v6 * bhi(p6.x); a2 += v6 * blo(p6.y); a3 += v6 * bhi(p6.y);
            a4 += v6 * blo(p6.z); a5 += v6 * bhi(p6.z); a6 += v6 * blo(p6.w); a7 += v6 * bhi(p6.w);
            a0 += v7 * blo(p7.x); a1 += v7 * bhi(p7.x); a2 += v7 * blo(p7.y); a3 += v7 * bhi(p7.y);
            a4 += v7 * blo(p7.z); a5 += v7 * bhi(p7.z); a6 += v7 * blo(p7.w); a7 += v7 * bhi(p7.w);
        }
    }

    float id = 1.0f / deg[row];
    a0 *= id; a1 *= id; a2 *= id; a3 *= id; a4 *= id; a5 *= id; a6 *= id; a7 *= id;

    float ss = a0 * a0 + a1 * a1 + a2 * a2 + a3 * a3 + a4 * a4 + a5 * a5 + a6 * a6 + a7 * a7;
#pragma unroll
    for (int m = 1; m <= 8; m <<= 1) ss += __shfl_xor(ss, m);
    float nrm = fmaxf(sqrtf(ss), 1e-12f);
    float w4 = weight / nrm;

    // combine: acc = s1*x1 + s2*x2 + s3*x3 + w4 * (f32 hop-4 row); x1..x3 are streams -> NT
    size_t xi = (size_t)row * 16 + sub;
    float w1 = s1[row], w2 = s2[row], w3 = s3[row];
    uiv4 q1 = __builtin_nontemporal_load((const uiv4*)&x1[xi]);
    uiv4 q2 = __builtin_nontemporal_load((const uiv4*)&x2[xi]);
    uiv4 q3 = __builtin_nontemporal_load((const uiv4*)&x3[xi]);
    float v[8];
    v[0] = w1 * blo(q1.x) + w2 * blo(q2.x) + w3 * blo(q3.x) + w4 * a0;
    v[1] = w1 * bhi(q1.x) + w2 * bhi(q2.x) + w3 * bhi(q3.x) + w4 * a1;
    v[2] = w1 * blo(q1.y) + w2 * blo(q2.y) + w3 * blo(q3.y) + w4 * a2;
    v[3] = w1 * bhi(q1.y) + w2 * bhi(q2.y) + w3 * bhi(q3.y) + w4 * a3;
    v[4] = w1 * blo(q1.z) + w2 * blo(q2.z) + w3 * blo(q3.z) + w4 * a4;
    v[5] = w1 * bhi(q1.z) + w2 * bhi(q2.z) + w3 * bhi(q3.z) + w4 * a5;
    v[6] = w1 * blo(q1.w) + w2 * blo(q2.w) + w3 * blo(q3.w) + w4 * a6;
    v[7] = w1 * bhi(q1.w) + w2 * bhi(q2.w) + w3 * bhi(q3.w) + w4 * a7;

    float4* out4 = (float4*)out;
    out4[(size_t)row * 32 + sub * 2]     = make_float4(v[0], v[1], v[2], v[3]);
    out4[(size_t)row * 32 + sub * 2 + 1] = make_float4(v[4], v[5], v[6], v[7]);

    int t = threadIdx.x;
#pragma unroll
    for (int j = 0; j < 8; ++j) {
        shs[t * 8 + j] = v[j];
        shq[t * 8 + j] = v[j] * v[j];
    }
    __syncthreads();
    if (t < DD) {
        int cs = t >> 3, cj = t & 7;
        float sacc = 0.0f, qacc = 0.0f;
        for (int g = 0; g < 16; ++g) {
            int src = (g * 16 + cs) * 8 + cj;
            sacc += shs[src];
            qacc += shq[src];
        }
        psum[(size_t)blockIdx.x * DD + t] = sacc;
        psumsq[(size_t)blockIdx.x * DD + t] = qacc;
    }
}

// ---------------- fold partials per column, compute mean/invstd ----------------
static __global__ __launch_bounds__(256) void fold_kernel(
    const float* __restrict__ psum, const float* __restrict__ psumsq,
    float* __restrict__ mean, float* __restrict__ invstd) {
    __shared__ double ss[256], qq[256];
    int c = blockIdx.x;
    int t = threadIdx.x;
    double s = 0.0, q = 0.0;
    for (int b = t; b < SPMM_NBLK; b += 256) {
        s += (double)psum[(size_t)b * DD + c];
        q += (double)psumsq[(size_t)b * DD + c];
    }
    ss[t] = s; qq[t] = q;
    __syncthreads();
    for (int off = 128; off > 0; off >>= 1) {
        if (t < off) { ss[t] += ss[t + off]; qq[t] += qq[t + off]; }
        __syncthreads();
    }
    if (t == 0) {
        double m = ss[0] / (double)NN;
        double var = (qq[0] - (double)NN * m * m) / (double)(NN - 1);
        if (var < 0.0) var = 0.0;
        double sd = sqrt(var);
        if (sd == 0.0) sd = 1.0;
        mean[c] = (float)m;
        invstd[c] = (float)(1.0 / sd);
    }
}

// ---------------- standardize in place (float4 vectorized) ----------------
static __global__ __launch_bounds__(256) void normalize_kernel(
    float* __restrict__ out, const float* __restrict__ mean, const float* __restrict__ invstd) {
    int i = blockIdx.x * blockDim.x + threadIdx.x;  // over NN*32 float4s
    int c4 = i & 31;
    float4 m = ((const float4*)mean)[c4];
    float4 is = ((const float4*)invstd)[c4];
    float4* out4 = (float4*)out;
    float4 v = out4[i];
    v.x = (v.x - m.x) * is.x;
    v.y = (v.y - m.y) * is.y;
    v.z = (v.z - m.z) * is.z;
    v.w = (v.w - m.w) * is.w;
    out4[i] = v;
}

extern "C" void kernel_launch(void* const* d_in, const int* in_sizes, int n_in,
                              void* d_out, int out_size, void* d_ws, size_t ws_size,
                              hipStream_t stream) {
    const int* erow = (const int*)d_in[0];
    const int* ecol = (const int*)d_in[1];
    const float* eval_ = (const float*)d_in[2];
    const float* R = (const float*)d_in[3];
    float* out = (float*)d_out;

    char* ws = (char*)d_ws;
    size_t off = 0;
    auto alloc = [&](size_t bytes) -> char* {
        char* p = ws + off;
        off += (bytes + 255) & ~(size_t)255;
        return p;
    };
    float* deg          = (float*)alloc(NN * sizeof(float));
    int* bucket_cursor  = (int*)alloc(NBKT * sizeof(int));
    int* row_start      = (int*)alloc((NN + 1) * sizeof(int));
    uint2* binned       = (uint2*)alloc((size_t)NBKT * BCAP * sizeof(uint2));
    uint2* csr          = (uint2*)alloc((size_t)NE * sizeof(uint2));
    uint4* x0           = (uint4*)alloc((size_t)NN * 16 * sizeof(uint4));  // bf16 packed
    uint4* x1           = (uint4*)alloc((size_t)NN * 16 * sizeof(uint4));
    uint4* x2           = (uint4*)alloc((size_t)NN * 16 * sizeof(uint4));
    uint4* x3           = (uint4*)alloc((size_t)NN * 16 * sizeof(uint4));
    float* s1           = (float*)alloc(NN * sizeof(float));
    float* s2           = (float*)alloc(NN * sizeof(float));
    float* s3           = (float*)alloc(NN * sizeof(float));
    float* psum         = (float*)alloc((size_t)SPMM_NBLK * DD * sizeof(float));
    float* psumsq       = (float*)alloc((size_t)SPMM_NBLK * DD * sizeof(float));
    float* meanbuf      = (float*)alloc(DD * sizeof(float));
    float* invstdb      = (float*)alloc(DD * sizeof(float));

    hipMemsetAsync(bucket_cursor, 0, NBKT * sizeof(int), stream);

    bin_kernel<<<NCHUNK, 256, 0, stream>>>(erow, ecol, eval_, bucket_cursor, binned);
    sort_kernel<<<NBKT, 256, 0, stream>>>(binned, bucket_cursor, csr, row_start, deg, R, x0);

    spmm_fused_kernel<<<SPMM_NBLK, 256, 0, stream>>>(row_start, csr, x0, deg, x1, s1, 1.0f);
    spmm_fused_kernel<<<SPMM_NBLK, 256, 0, stream>>>(row_start, csr, x1, deg, x2, s2, 1.0f);
    spmm_fused_kernel<<<SPMM_NBLK, 256, 0, stream>>>(row_start, csr, x2, deg, x3, s3, 7.81f);
    spmm_last_kernel<<<SPMM_NBLK, 256, 0, stream>>>(row_start, csr, x3, deg, x1, x2, x3,
                                                    s1, s2, s3, out, psum, psumsq, 45.28f);

    fold_kernel<<<DD, 256, 0, stream>>>(psum, psumsq, meanbuf, invstdb);
    normalize_kernel<<<NN * 32 / 256, 256, 0, stream>>>(out, meanbuf, invstdb);
}